// Round 8
// baseline (546.166 us; speedup 1.0000x reference)
//
#include <hip/hip_runtime.h>
#include <cstdint>

// ---------- types ----------
typedef float f32x4 __attribute__((ext_vector_type(4)));
typedef __bf16 bf16x8 __attribute__((ext_vector_type(8)));

#define AS1 __attribute__((address_space(1)))
#define AS3 __attribute__((address_space(3)))

__device__ __forceinline__ void gld_lds16(const void* g, void* l) {
    __builtin_amdgcn_global_load_lds((const AS1 void*)g, (AS3 void*)l, 16, 0, 0);
}

__device__ __forceinline__ unsigned short f2bf(float f) {  // RNE f32->bf16
    unsigned u = __builtin_bit_cast(unsigned, f);
    u = u + 0x7fffu + ((u >> 16) & 1u);
    return (unsigned short)(u >> 16);
}
__device__ __forceinline__ float bf2f(unsigned short h) {
    unsigned u = ((unsigned)h) << 16;
    return __builtin_bit_cast(float, u);
}

__device__ __forceinline__ void bar() {
    asm volatile("" ::: "memory");
    __builtin_amdgcn_s_barrier();
    asm volatile("" ::: "memory");
}

#define WAITVM(n) asm volatile("s_waitcnt vmcnt(" #n ")" ::: "memory")
#define LGKM0     asm volatile("s_waitcnt lgkmcnt(0)" ::: "memory")
#define SCHED0    __builtin_amdgcn_sched_barrier(0)

// ---------- 8-phase GEMM (R6 structure) + ABL=5 diagnostic probe ----------
// ABL 0: real (identical to R6 gemm8q).
// ABL 5: PROBE — same ds_read + lgkmcnt + setprio + MFMA per phase, but NO
//   stage, NO vmcnt, NO barriers; K-loop repeated 8x. Measures the pure
//   compute+LDS floor of the structure. Output is garbage; host overwrites.
template<int BN, int MODE, int SWZ, int ABL>
__global__ __launch_bounds__(512, 2) void gemm8q(
    const unsigned short* __restrict__ A, long lda, long sAb,
    const unsigned short* __restrict__ B, long ldb, long sBb,
    void* C, long ldc, long sCb,
    const float* add, long ldadd, long sAddb,
    const float* __restrict__ bias, int K)
{
    constexpr int NR   = BN / 64;
    constexpr int ABUF = 256 * 128;
    constexpr int BBUF = BN * 128;
    constexpr int BUF  = ABUF + BBUF;
    __shared__ char sm[2 * BUF];
    const int tid = threadIdx.x, lane = tid & 63, wid = tid >> 6;
    const int wr = wid >> 2, wc = wid & 3;

    int bx, by;
    long zb;
    if constexpr (SWZ == 1) {
        const int d   = blockIdx.x + ((blockIdx.y + (blockIdx.z << 3)) << 3);
        const int xcd = d & 7, j = d >> 3;
        zb = j >> 3;
        const int pos = j & 7;
        by = ((xcd & 1) << 2) + (pos >> 1);
        bx = ((xcd >> 1) << 1) + (pos & 1);
    } else {
        zb = blockIdx.z;
        const int nwg  = gridDim.x * gridDim.y;
        const int orig = blockIdx.y * gridDim.x + blockIdx.x;
        const int q8 = nwg >> 3, r8 = nwg & 7;
        const int xcd = orig & 7;
        const int wg  = (xcd < r8 ? xcd * (q8 + 1) : r8 * (q8 + 1) + (xcd - r8) * q8) + (orig >> 3);
        bx = wg % gridDim.x; by = wg / gridDim.x;
    }

    const char* Ab = (const char*)(A + zb * sAb + (long)by * 256 * lda);
    const char* Bb = (const char*)(B + zb * sBb + (long)bx * BN * ldb);
    const long ldaB = lda * 2, ldbB = ldb * 2;

    auto stageA = [&](int kt, int p, int half) {
#pragma unroll
        for (int i = 0; i < 2; ++i) {
            const int r0 = half * 64 + i * 128;
            const int r  = r0 + (tid >> 3);
            gld_lds16(Ab + (long)r * ldaB + (long)kt * 128 + (((tid & 7) ^ (r & 7)) << 4),
                      sm + p * BUF + r0 * 128 + wid * 1024);
        }
    };
    auto stageB = [&](int kt, int p, int ks) {
#pragma unroll
        for (int i = 0; i < BN / 128; ++i) {
            const int r = i * 128 + (tid >> 2);
            gld_lds16(Bb + (long)r * ldbB + (long)kt * 128 + ks * 64 + (((tid & 3) ^ ((r >> 1) & 3)) << 4),
                      sm + p * BUF + ABUF + ks * BN * 64 + i * 8192 + wid * 1024);
        }
    };

    f32x4 acc[8][NR] = {};
    const int NT = K / 64;

    // ds_read + MFMA core of one phase (shared by real and probe paths)
#define PHASE_CORE(MH, KS)                                                      \
    bf16x8 af[4]; bf16x8 bfr[NR];                                               \
    _Pragma("unroll")                                                           \
    for (int m = 0; m < 4; ++m) {                                               \
        const int R = wr * 128 + ((MH) * 4 + m) * 16 + (lane & 15);             \
        const int cc = (((KS) * 4 + (lane >> 4)) ^ (R & 7)) << 4;               \
        af[m] = *(const bf16x8*)(bufp + R * 128 + cc);                          \
    }                                                                           \
    _Pragma("unroll")                                                           \
    for (int n = 0; n < NR; ++n) {                                              \
        const int R = wc * 16 * NR + n * 16 + (lane & 15);                      \
        const int cc = ((lane >> 4) ^ ((R >> 1) & 3)) << 4;                     \
        bfr[n] = *(const bf16x8*)(bufp + ABUF + (KS) * BN * 64 + R * 64 + cc);  \
    }

#define PHASE_MFMA(MH)                                                          \
    __builtin_amdgcn_s_setprio(1);                                              \
    _Pragma("unroll")                                                           \
    for (int m = 0; m < 4; ++m)                                                 \
    _Pragma("unroll")                                                           \
        for (int n = 0; n < NR; ++n)                                            \
            acc[(MH) * 4 + m][n] = __builtin_amdgcn_mfma_f32_16x16x32_bf16(     \
                af[m], bfr[n], acc[(MH) * 4 + m][n], 0, 0, 0);                  \
    __builtin_amdgcn_s_setprio(0);

    if constexpr (ABL == 5) {
        // -------- PROBE: no stage, no vmcnt, no barriers; repeat 8x --------
#pragma unroll 1
        for (int rep = 0; rep < 8; ++rep) {
#pragma unroll 1
            for (int t = 0; t < NT; ++t) {
                const char* bufp = sm + (t & 1) * BUF;
                { PHASE_CORE(0, 0) LGKM0; SCHED0; PHASE_MFMA(0) }
                { PHASE_CORE(1, 0) LGKM0; SCHED0; PHASE_MFMA(1) }
                { PHASE_CORE(0, 1) LGKM0; SCHED0; PHASE_MFMA(0) }
                { PHASE_CORE(1, 1) LGKM0; SCHED0; PHASE_MFMA(1) }
            }
        }
    } else {
        // -------- REAL: exact R6 schedule --------
#define PHASE(MH, KS, STAGE_STMT, WAIT_STMT) do {                               \
    PHASE_CORE(MH, KS)                                                          \
    STAGE_STMT;                                                                 \
    WAIT_STMT;                                                                  \
    bar();                                                                      \
    LGKM0; SCHED0;                                                              \
    PHASE_MFMA(MH)                                                              \
    bar();                                                                      \
} while (0)

        stageA(0, 0, 0); stageA(0, 0, 1); stageB(0, 0, 0); stageB(0, 0, 1);
        if (NT > 1) { stageB(1, 1, 0); stageA(1, 1, 0); }
        if constexpr (BN == 256) WAITVM(4); else WAITVM(3);
        bar();

#pragma unroll 1
        for (int t = 0; t < NT; ++t) {
            const int p = t & 1;
            const char* bufp = sm + p * BUF;
            PHASE(0, 0, { if (t + 1 < NT) stageA(t + 1, p ^ 1, 1); }, {});
            PHASE(1, 0, { if (t + 1 < NT) stageB(t + 1, p ^ 1, 1); }, {});
            PHASE(0, 1, { if (t + 2 < NT) stageB(t + 2, p, 0); }, {});
            PHASE(1, 1, { if (t + 2 < NT) stageA(t + 2, p, 0); },
                  { if (t + 2 < NT) { if constexpr (BN == 256) WAITVM(4); else WAITVM(3); }
                    else if (t + 1 < NT) WAITVM(0); });
        }
#undef PHASE
    }
#undef PHASE_CORE
#undef PHASE_MFMA

    // epilogue
    const long row0 = (long)by * 256 + wr * 128 + (lane >> 4) * 4;
    const long col0 = (long)bx * BN + wc * 16 * NR + (lane & 15);
#pragma unroll
    for (int m = 0; m < 8; ++m)
#pragma unroll
        for (int n = 0; n < NR; ++n)
#pragma unroll
            for (int j = 0; j < 4; ++j) {
                const long r = row0 + m * 16 + j;
                const long c = col0 + n * 16;
                const float v = acc[m][n][j];
                if (MODE == 0) {
                    ((float*)C)[zb * sCb + r * ldc + c] = v;
                } else if (MODE == 1) {
                    ((float*)C)[zb * sCb + r * ldc + c] = v + add[zb * sAddb + r * ldadd + c];
                } else if (MODE == 2) {
                    float tt = v + bias[c];
                    float gl = 0.5f * tt * (1.0f + erff(tt * 0.70710678118654752f));
                    ((unsigned short*)C)[zb * sCb + r * ldc + c] = f2bf(gl);
                } else {
                    ((float*)C)[zb * sCb + r * ldc + c] = v + bias[c] + add[zb * sAddb + r * ldadd + c];
                }
            }
}

// ---------- LayerNorm ----------
__global__ __launch_bounds__(256) void ln_kernel(
    const float* __restrict__ x, const float* __restrict__ gamma, const float* __restrict__ beta,
    unsigned short* __restrict__ out, int ldout, float* qout, int pad)
{
    const int tid = threadIdx.x;
    const long row = blockIdx.x;
    float4 v = ((const float4*)(x + row * 1024))[tid];
    float s = v.x + v.y + v.z + v.w;
    float s2 = v.x * v.x + v.y * v.y + v.z * v.z + v.w * v.w;
#pragma unroll
    for (int off = 32; off; off >>= 1) {
        s  += __shfl_down(s, off);
        s2 += __shfl_down(s2, off);
    }
    __shared__ float red[12];
    const int lane = tid & 63, wid = tid >> 6;
    if (lane == 0) { red[wid] = s; red[4 + wid] = s2; }
    __syncthreads();
    s  = red[0] + red[1] + red[2] + red[3];
    s2 = red[4] + red[5] + red[6] + red[7];
    const float mu = s * (1.0f / 1024.0f);
    const float var = s2 * (1.0f / 1024.0f) - mu * mu;
    const float rs = rsqrtf(var + 1e-5f);
    const float4 g = ((const float4*)gamma)[tid];
    const float4 b = ((const float4*)beta)[tid];
    unsigned short o0 = f2bf((v.x - mu) * rs * g.x + b.x);
    unsigned short o1 = f2bf((v.y - mu) * rs * g.y + b.y);
    unsigned short o2 = f2bf((v.z - mu) * rs * g.z + b.z);
    unsigned short o3 = f2bf((v.w - mu) * rs * g.w + b.w);
    ushort4 ov; ov.x = o0; ov.y = o1; ov.z = o2; ov.w = o3;
    ((ushort4*)(out + row * (long)ldout))[tid] = ov;
    if (pad && tid < 32) out[row * (long)ldout + 1056 + tid] = 0;
    if (qout) {
        float y0 = bf2f(o0), y1 = bf2f(o1), y2 = bf2f(o2), y3 = bf2f(o3);
        float sq = y0 * y0 + y1 * y1 + y2 * y2 + y3 * y3;
#pragma unroll
        for (int off = 32; off; off >>= 1) sq += __shfl_down(sq, off);
        if (lane == 0) red[8 + wid] = sq;
        __syncthreads();
        if (tid == 0) qout[row] = red[8] + red[9] + red[10] + red[11];
    }
}

// ---------- u = hn @ L ----------
__global__ __launch_bounds__(256) void u_kernel(
    unsigned short* __restrict__ z, const float* __restrict__ L, float* __restrict__ q)
{
    const int tid = threadIdx.x;
    const long row = blockIdx.x;
    __shared__ float hn[1024];
    __shared__ float part[8][32];
    ushort4 uv = ((const ushort4*)(z + row * 1088))[tid];
    hn[tid * 4 + 0] = bf2f(uv.x);
    hn[tid * 4 + 1] = bf2f(uv.y);
    hn[tid * 4 + 2] = bf2f(uv.z);
    hn[tid * 4 + 3] = bf2f(uv.w);
    __syncthreads();
    const int j = tid & 31, grp = tid >> 5;
    float acc = 0.f;
    const float* Lp = L + j;
#pragma unroll 4
    for (int d = grp * 128; d < grp * 128 + 128; ++d)
        acc += hn[d] * Lp[(long)d * 32];
    part[grp][j] = acc;
    __syncthreads();
    if (tid < 32) {
        float u = 0.f;
#pragma unroll
        for (int g2 = 0; g2 < 8; ++g2) u += part[g2][tid];
        unsigned short ub = f2bf(u);
        z[row * 1088 + 1024 + tid] = ub;
        float uf = bf2f(ub);
        part[0][tid] = uf * uf;
    }
    __syncthreads();
    if (tid == 0) {
        float sq = 0.f;
#pragma unroll
        for (int t2 = 0; t2 < 32; ++t2) sq += part[0][t2];
        q[row] += sq;
    }
}

// ---------- softmax ----------
__global__ __launch_bounds__(256) void softmax_kernel(
    float* S, const float* qb)
{
    const int tid = threadIdx.x;
    const long i = blockIdx.x, bl = blockIdx.y;
    float* Sr = S + (bl * 2048 + i) * 2048;
    const float* qr = qb + bl * 2048;
    float l[8];
    float mx = -1e30f;
#pragma unroll
    for (int c2 = 0; c2 < 8; ++c2) {
        const int jj = tid + c2 * 256;
        l[c2] = 2.0f * Sr[jj] - qr[jj];
        mx = fmaxf(mx, l[c2]);
    }
#pragma unroll
    for (int off = 32; off; off >>= 1) mx = fmaxf(mx, __shfl_xor(mx, off));
    __shared__ float red[8];
    const int lane = tid & 63, wid = tid >> 6;
    if (lane == 0) red[wid] = mx;
    __syncthreads();
    mx = fmaxf(fmaxf(red[0], red[1]), fmaxf(red[2], red[3]));
    float sum = 0.f;
#pragma unroll
    for (int c2 = 0; c2 < 8; ++c2) { l[c2] = __expf(l[c2] - mx); sum += l[c2]; }
#pragma unroll
    for (int off = 32; off; off >>= 1) sum += __shfl_xor(sum, off);
    if (lane == 0) red[4 + wid] = sum;
    __syncthreads();
    sum = red[4] + red[5] + red[6] + red[7];
    const float inv = 1.0f / sum;
    unsigned short* Pr = (unsigned short*)S + (bl * 2048 + i) * 4096;
#pragma unroll
    for (int c2 = 0; c2 < 8; ++c2)
        Pr[tid + c2 * 256] = f2bf(l[c2] * inv);
}

// ---------- Vt transpose ----------
__global__ __launch_bounds__(256) void transpose_v_kernel(
    const unsigned short* __restrict__ z, unsigned short* __restrict__ Vt, long sVtb)
{
    __shared__ unsigned short t[32][33];
    const int tid = threadIdx.x;
    const int tx = tid & 31, ty = tid >> 5;
    const long b = blockIdx.z;
    const long k0 = (long)blockIdx.x * 32, n0 = (long)blockIdx.y * 32;
#pragma unroll
    for (int r = 0; r < 32; r += 8)
        t[r + ty][tx] = z[(b * 2048 + k0 + r + ty) * 1088 + n0 + tx];
    __syncthreads();
#pragma unroll
    for (int r = 0; r < 32; r += 8)
        Vt[b * sVtb + (n0 + r + ty) * 2048 + k0 + tx] = t[tx][r + ty];
}

// ---------- weight cast-transpose ----------
__global__ __launch_bounds__(256) void cast_transpose_kernel(
    const float* __restrict__ W, unsigned short* __restrict__ Wt, int rows, int cols)
{
    __shared__ float t[32][33];
    const int tid = threadIdx.x;
    const int tx = tid & 31, ty = tid >> 5;
    const long r0 = (long)blockIdx.y * 32, c0 = (long)blockIdx.x * 32;
#pragma unroll
    for (int r = 0; r < 32; r += 8)
        t[r + ty][tx] = W[(r0 + r + ty) * (long)cols + c0 + tx];
    __syncthreads();
#pragma unroll
    for (int r = 0; r < 32; r += 8)
        Wt[(c0 + r + ty) * (long)rows + r0 + tx] = f2bf(t[tx][r + ty]);
}

// ---------- host (R6 + one diagnostic probe launch) ----------
extern "C" void kernel_launch(void* const* d_in, const int* in_sizes, int n_in,
                              void* d_out, int out_size, void* d_ws, size_t ws_size,
                              hipStream_t stream)
{
    const float* x   = (const float*)d_in[0];
    const float* L   = (const float*)d_in[1];
    const float* W1  = (const float*)d_in[2];
    const float* b1  = (const float*)d_in[3];
    const float* W2  = (const float*)d_in[4];
    const float* b2  = (const float*)d_in[5];
    const float* g1  = (const float*)d_in[6];
    const float* be1 = (const float*)d_in[7];
    const float* g2  = (const float*)d_in[8];
    const float* be2 = (const float*)d_in[9];
    float* out = (float*)d_out;
    unsigned short* z = (unsigned short*)d_out;

    char* wsp = (char*)d_ws;
    float* q = (float*)wsp;
    char* pool = wsp + 32768;
    unsigned short* Vt   = (unsigned short*)pool;
    float*          Smat = (float*)(pool + 16777216);
    unsigned short* W1t = (unsigned short*)pool;
    unsigned short* W2t = (unsigned short*)(pool + 8388608);
    unsigned short* hm  = (unsigned short*)(pool + 16777216);
    unsigned short* hid = (unsigned short*)(pool + 33554432);
    const bool fullMLP = ws_size >= (size_t)32768 + 100663296 + 65536;

    ln_kernel<<<8192, 256, 0, stream>>>(x, g1, be1, z, 1088, q, 1);
    u_kernel<<<8192, 256, 0, stream>>>(z, L, q);

    transpose_v_kernel<<<dim3(64, 32, 4), 256, 0, stream>>>(z, Vt, (long)1024 * 2048);

    // DIAGNOSTIC PROBE (ABL=5): compute+LDS floor of the S-GEMM structure,
    // repeated 8x. Writes garbage to Smat; real S-GEMM below overwrites it.
    gemm8q<256, 0, 1, 5><<<dim3(8, 8, 4), 512, 0, stream>>>(
        z, 1088, (long)2048 * 1088,
        z, 1088, (long)2048 * 1088,
        Smat, 2048, (long)2048 * 2048,
        nullptr, 0, 0, nullptr, 1088);

    gemm8q<256, 0, 1, 0><<<dim3(8, 8, 4), 512, 0, stream>>>(
        z, 1088, (long)2048 * 1088,
        z, 1088, (long)2048 * 1088,
        Smat, 2048, (long)2048 * 2048,
        nullptr, 0, 0, nullptr, 1088);
    softmax_kernel<<<dim3(2048, 4), 256, 0, stream>>>(Smat, q);
    gemm8q<128, 1, 1, 0><<<dim3(8, 8, 4), 512, 0, stream>>>(
        (const unsigned short*)Smat, 4096, (long)2048 * 4096,
        Vt, 2048, (long)1024 * 2048,
        out, 1024, (long)2048 * 1024,
        x, 1024, (long)2048 * 1024,
        nullptr, 2048);

    cast_transpose_kernel<<<dim3(128, 32), 256, 0, stream>>>(W1, W1t, 1024, 4096);
    cast_transpose_kernel<<<dim3(32, 128), 256, 0, stream>>>(W2, W2t, 4096, 1024);
    ln_kernel<<<8192, 256, 0, stream>>>(out, g2, be2, hm, 1024, nullptr, 0);
    if (fullMLP) {
        gemm8q<256, 2, 0, 0><<<dim3(16, 32, 1), 512, 0, stream>>>(
            hm, 1024, 0, W1t, 1024, 0,
            hid, 4096, 0, nullptr, 0, 0, b1, 1024);
        gemm8q<128, 3, 0, 0><<<dim3(8, 32, 1), 512, 0, stream>>>(
            hid, 4096, 0, W2t, 4096, 0,
            out, 1024, 0, out, 1024, 0, b2, 4096);
    } else {
        for (int c = 0; c < 2; ++c) {
            const unsigned short* hmc = hm + (size_t)c * 4096 * 1024;
            float* oc = out + (size_t)c * 4096 * 1024;
            gemm8q<256, 2, 0, 0><<<dim3(32, 16, 1), 512, 0, stream>>>(
                hmc, 1024, 0, W1t, 1024, 0,
                hid, 4096, 0, nullptr, 0, 0, b1, 1024);
            gemm8q<128, 3, 0, 0><<<dim3(8, 16, 1), 512, 0, stream>>>(
                hid, 4096, 0, W2t, 4096, 0,
                oc, 1024, 0, oc, 1024, 0, b2, 4096);
        }
    }
}

// Round 9
// 477.831 us; speedup vs baseline: 1.1430x; 1.1430x over previous
//
#include <hip/hip_runtime.h>
#include <cstdint>

// ---------- types ----------
typedef float f32x4 __attribute__((ext_vector_type(4)));
typedef __bf16 bf16x8 __attribute__((ext_vector_type(8)));

#define AS1 __attribute__((address_space(1)))
#define AS3 __attribute__((address_space(3)))

__device__ __forceinline__ void gld_lds16(const void* g, void* l) {
    __builtin_amdgcn_global_load_lds((const AS1 void*)g, (AS3 void*)l, 16, 0, 0);
}

__device__ __forceinline__ unsigned short f2bf(float f) {  // RNE f32->bf16
    unsigned u = __builtin_bit_cast(unsigned, f);
    u = u + 0x7fffu + ((u >> 16) & 1u);
    return (unsigned short)(u >> 16);
}
__device__ __forceinline__ float bf2f(unsigned short h) {
    unsigned u = ((unsigned)h) << 16;
    return __builtin_bit_cast(float, u);
}

__device__ __forceinline__ void bar() {
    asm volatile("" ::: "memory");
    __builtin_amdgcn_s_barrier();
    asm volatile("" ::: "memory");
}

#define WAITVM(n) asm volatile("s_waitcnt vmcnt(" #n ")" ::: "memory")
#define LGKM0     asm volatile("s_waitcnt lgkmcnt(0)" ::: "memory")
#define SCHED0    __builtin_amdgcn_sched_barrier(0)

// ---------- 4-ring minimal-sync GEMM: C = A @ B^T, bf16 in, f32 accum ------
// 256xBN tile, BK=32 (64B LDS rows), 8 waves (2M x 4N).
// LDS: FOUR buffers (A 16KB + B BN*64B) = 128KB (BN=256) / 96KB (BN=128).
// Per K-tile: 2 free-running phases {4+NR ds_read_b128, lgkmcnt(0), 16 MFMA},
// stage of tile t+3 spread across them, then ONE counted vmcnt + ONE barrier.
// That is 1 barrier per 32 MFMA (vs 8 in R5-R7) — R8's probe proved the
// phase core alone runs at 71% MfmaUtil; sync was ~80% of kernel time.
// WAR proof: stage target buf (t+3)&3 = (t-1)&3; tile t-1 readers drained
//   (per-wave lgkmcnt(0)) before the bar that ended t-1; stages issue after.
// RAW proof: end-of-t vmcnt leaves only stages issued during {t-1,t}
//   (for t+2,t+3) outstanding -> tile t+1 fully landed; 2-tile latency cover.
// Swizzle: chunk' = chunk ^ ((row>>1)&3), source-side; LDS linear (rule 21);
//   frag reads use cc = (lane>>4)^((lane>>1)&3) -> 2 lanes/bank-set = free.
// ABL 0: real.  ABL 6: probe - stages issued, NO vmcnt/barriers, 4 reps.
// MODE 0: C f32 = acc; 1: +add; 2: bf16 gelu(acc+bias); 3: f32 acc+bias+add
template<int BN, int MODE, int ABL>
__global__ __launch_bounds__(512, 2) void gemm4r(
    const unsigned short* __restrict__ A, long lda, long sAb,
    const unsigned short* __restrict__ B, long ldb, long sBb,
    void* C, long ldc, long sCb,
    const float* add, long ldadd, long sAddb,
    const float* __restrict__ bias, int K)
{
    constexpr int NR   = BN / 64;
    constexpr int ABUF = 256 * 64;         // 16 KB
    constexpr int BBUF = BN * 64;          // 16/8 KB
    constexpr int BUF  = ABUF + BBUF;
    __shared__ char sm[4 * BUF];
    const int tid = threadIdx.x, lane = tid & 63, wid = tid >> 6;
    const int wr = wid >> 2, wc = wid & 3;

    const long zb = blockIdx.z;
    // m204 bijective XCD swizzle
    const int nwg  = gridDim.x * gridDim.y;
    const int orig = blockIdx.y * gridDim.x + blockIdx.x;
    const int q8 = nwg >> 3, r8 = nwg & 7;
    const int xcd = orig & 7;
    const int wg  = (xcd < r8 ? xcd * (q8 + 1) : r8 * (q8 + 1) + (xcd - r8) * q8) + (orig >> 3);
    const int bx = wg % gridDim.x, by = wg / gridDim.x;

    const char* Ab = (const char*)(A + zb * sAb + (long)by * 256 * lda);
    const char* Bb = (const char*)(B + zb * sBb + (long)bx * BN * ldb);
    const long ldaB = lda * 2, ldbB = ldb * 2;

    // stage one K-tile's A (256 rows x 64B) / B (BN rows x 64B) into buffer b.
    // LDS dest linear (tid*16); global source chunk pre-swizzled.
    const long gsw = (long)(((tid & 3) ^ ((tid >> 3) & 3)) << 4);
    auto stageA = [&](int kt, int b) {
#pragma unroll
        for (int i = 0; i < 2; ++i) {
            const int r = i * 128 + (tid >> 2);
            gld_lds16(Ab + (long)r * ldaB + (long)kt * 64 + gsw,
                      sm + b * BUF + i * 8192 + wid * 1024);
        }
    };
    auto stageB = [&](int kt, int b) {
#pragma unroll
        for (int i = 0; i < BN / 128; ++i) {
            const int r = i * 128 + (tid >> 2);
            gld_lds16(Bb + (long)r * ldbB + (long)kt * 64 + gsw,
                      sm + b * BUF + ABUF + i * 8192 + wid * 1024);
        }
    };

    f32x4 acc[8][NR] = {};
    const int NT = K / 32;
    const int cc = ((lane >> 4) ^ ((lane >> 1) & 3)) << 4;   // frag k-chunk

#define PHASE_CORE(MH)                                                          \
    bf16x8 af[4]; bf16x8 bfr[NR];                                               \
    _Pragma("unroll")                                                           \
    for (int m = 0; m < 4; ++m) {                                               \
        const int R = wr * 128 + ((MH) * 4 + m) * 16 + (lane & 15);             \
        af[m] = *(const bf16x8*)(bufp + R * 64 + cc);                           \
    }                                                                           \
    _Pragma("unroll")                                                           \
    for (int n = 0; n < NR; ++n) {                                              \
        const int R = wc * 16 * NR + n * 16 + (lane & 15);                      \
        bfr[n] = *(const bf16x8*)(bufp + ABUF + R * 64 + cc);                   \
    }

#define PHASE_MFMA(MH)                                                          \
    __builtin_amdgcn_s_setprio(1);                                              \
    _Pragma("unroll")                                                           \
    for (int m = 0; m < 4; ++m)                                                 \
    _Pragma("unroll")                                                           \
        for (int n = 0; n < NR; ++n)                                            \
            acc[(MH) * 4 + m][n] = __builtin_amdgcn_mfma_f32_16x16x32_bf16(     \
                af[m], bfr[n], acc[(MH) * 4 + m][n], 0, 0, 0);                  \
    __builtin_amdgcn_s_setprio(0);

    if constexpr (ABL == 6) {
        // probe: stages issued, zero sync, 4 reps (garbage output)
#pragma unroll 1
        for (int rep = 0; rep < 4; ++rep) {
#pragma unroll 1
            for (int t = 0; t < NT; ++t) {
                const char* bufp = sm + (t & 3) * BUF;
                { PHASE_CORE(0) if (t + 3 < NT) stageA(t + 3, (t + 3) & 3);
                  LGKM0; SCHED0; PHASE_MFMA(0) }
                { PHASE_CORE(1) if (t + 3 < NT) stageB(t + 3, (t + 3) & 3);
                  LGKM0; SCHED0; PHASE_MFMA(1) }
            }
        }
    } else {
        // prologue: tiles 0,1,2
        stageA(0, 0); stageB(0, 0);
        stageA(1, 1); stageB(1, 1);
        stageA(2, 2); stageB(2, 2);
        if constexpr (BN == 256) WAITVM(8); else WAITVM(6);   // tile0 landed
        bar();

#pragma unroll 1
        for (int t = 0; t < NT; ++t) {
            const char* bufp = sm + (t & 3) * BUF;
            { PHASE_CORE(0) if (t + 3 < NT) stageA(t + 3, (t + 3) & 3);
              LGKM0; SCHED0; PHASE_MFMA(0) }
            { PHASE_CORE(1) if (t + 3 < NT) stageB(t + 3, (t + 3) & 3);
              LGKM0; SCHED0; PHASE_MFMA(1) }
            if (t + 1 < NT) {                 // single tile-end sync point
                if (t + 3 < NT)      { if constexpr (BN == 256) WAITVM(8); else WAITVM(6); }
                else if (t + 2 < NT) { if constexpr (BN == 256) WAITVM(4); else WAITVM(3); }
                else                 WAITVM(0);
                bar();
            }
        }
    }
#undef PHASE_CORE
#undef PHASE_MFMA

    // epilogue: C/D layout col=lane&15, row=(lane>>4)*4+j
    const long row0 = (long)by * 256 + wr * 128 + (lane >> 4) * 4;
    const long col0 = (long)bx * BN + wc * 16 * NR + (lane & 15);
#pragma unroll
    for (int m = 0; m < 8; ++m)
#pragma unroll
        for (int n = 0; n < NR; ++n)
#pragma unroll
            for (int j = 0; j < 4; ++j) {
                const long r = row0 + m * 16 + j;
                const long c = col0 + n * 16;
                const float v = acc[m][n][j];
                if (MODE == 0) {
                    ((float*)C)[zb * sCb + r * ldc + c] = v;
                } else if (MODE == 1) {
                    ((float*)C)[zb * sCb + r * ldc + c] = v + add[zb * sAddb + r * ldadd + c];
                } else if (MODE == 2) {
                    float tt = v + bias[c];
                    float gl = 0.5f * tt * (1.0f + erff(tt * 0.70710678118654752f));
                    ((unsigned short*)C)[zb * sCb + r * ldc + c] = f2bf(gl);
                } else {
                    ((float*)C)[zb * sCb + r * ldc + c] = v + bias[c] + add[zb * sAddb + r * ldadd + c];
                }
            }
}

// ---------- LayerNorm ----------
__global__ __launch_bounds__(256) void ln_kernel(
    const float* __restrict__ x, const float* __restrict__ gamma, const float* __restrict__ beta,
    unsigned short* __restrict__ out, int ldout, float* qout, int pad)
{
    const int tid = threadIdx.x;
    const long row = blockIdx.x;
    float4 v = ((const float4*)(x + row * 1024))[tid];
    float s = v.x + v.y + v.z + v.w;
    float s2 = v.x * v.x + v.y * v.y + v.z * v.z + v.w * v.w;
#pragma unroll
    for (int off = 32; off; off >>= 1) {
        s  += __shfl_down(s, off);
        s2 += __shfl_down(s2, off);
    }
    __shared__ float red[12];
    const int lane = tid & 63, wid = tid >> 6;
    if (lane == 0) { red[wid] = s; red[4 + wid] = s2; }
    __syncthreads();
    s  = red[0] + red[1] + red[2] + red[3];
    s2 = red[4] + red[5] + red[6] + red[7];
    const float mu = s * (1.0f / 1024.0f);
    const float var = s2 * (1.0f / 1024.0f) - mu * mu;
    const float rs = rsqrtf(var + 1e-5f);
    const float4 g = ((const float4*)gamma)[tid];
    const float4 b = ((const float4*)beta)[tid];
    unsigned short o0 = f2bf((v.x - mu) * rs * g.x + b.x);
    unsigned short o1 = f2bf((v.y - mu) * rs * g.y + b.y);
    unsigned short o2 = f2bf((v.z - mu) * rs * g.z + b.z);
    unsigned short o3 = f2bf((v.w - mu) * rs * g.w + b.w);
    ushort4 ov; ov.x = o0; ov.y = o1; ov.z = o2; ov.w = o3;
    ((ushort4*)(out + row * (long)ldout))[tid] = ov;
    if (pad && tid < 32) out[row * (long)ldout + 1056 + tid] = 0;
    if (qout) {
        float y0 = bf2f(o0), y1 = bf2f(o1), y2 = bf2f(o2), y3 = bf2f(o3);
        float sq = y0 * y0 + y1 * y1 + y2 * y2 + y3 * y3;
#pragma unroll
        for (int off = 32; off; off >>= 1) sq += __shfl_down(sq, off);
        if (lane == 0) red[8 + wid] = sq;
        __syncthreads();
        if (tid == 0) qout[row] = red[8] + red[9] + red[10] + red[11];
    }
}

// ---------- u = hn @ L ----------
__global__ __launch_bounds__(256) void u_kernel(
    unsigned short* __restrict__ z, const float* __restrict__ L, float* __restrict__ q)
{
    const int tid = threadIdx.x;
    const long row = blockIdx.x;
    __shared__ float hn[1024];
    __shared__ float part[8][32];
    ushort4 uv = ((const ushort4*)(z + row * 1088))[tid];
    hn[tid * 4 + 0] = bf2f(uv.x);
    hn[tid * 4 + 1] = bf2f(uv.y);
    hn[tid * 4 + 2] = bf2f(uv.z);
    hn[tid * 4 + 3] = bf2f(uv.w);
    __syncthreads();
    const int j = tid & 31, grp = tid >> 5;
    float acc = 0.f;
    const float* Lp = L + j;
#pragma unroll 4
    for (int d = grp * 128; d < grp * 128 + 128; ++d)
        acc += hn[d] * Lp[(long)d * 32];
    part[grp][j] = acc;
    __syncthreads();
    if (tid < 32) {
        float u = 0.f;
#pragma unroll
        for (int g2 = 0; g2 < 8; ++g2) u += part[g2][tid];
        unsigned short ub = f2bf(u);
        z[row * 1088 + 1024 + tid] = ub;
        float uf = bf2f(ub);
        part[0][tid] = uf * uf;
    }
    __syncthreads();
    if (tid == 0) {
        float sq = 0.f;
#pragma unroll
        for (int t2 = 0; t2 < 32; ++t2) sq += part[0][t2];
        q[row] += sq;
    }
}

// ---------- softmax ----------
__global__ __launch_bounds__(256) void softmax_kernel(
    float* S, const float* qb)
{
    const int tid = threadIdx.x;
    const long i = blockIdx.x, bl = blockIdx.y;
    float* Sr = S + (bl * 2048 + i) * 2048;
    const float* qr = qb + bl * 2048;
    float l[8];
    float mx = -1e30f;
#pragma unroll
    for (int c2 = 0; c2 < 8; ++c2) {
        const int jj = tid + c2 * 256;
        l[c2] = 2.0f * Sr[jj] - qr[jj];
        mx = fmaxf(mx, l[c2]);
    }
#pragma unroll
    for (int off = 32; off; off >>= 1) mx = fmaxf(mx, __shfl_xor(mx, off));
    __shared__ float red[8];
    const int lane = tid & 63, wid = tid >> 6;
    if (lane == 0) red[wid] = mx;
    __syncthreads();
    mx = fmaxf(fmaxf(red[0], red[1]), fmaxf(red[2], red[3]));
    float sum = 0.f;
#pragma unroll
    for (int c2 = 0; c2 < 8; ++c2) { l[c2] = __expf(l[c2] - mx); sum += l[c2]; }
#pragma unroll
    for (int off = 32; off; off >>= 1) sum += __shfl_xor(sum, off);
    if (lane == 0) red[4 + wid] = sum;
    __syncthreads();
    sum = red[4] + red[5] + red[6] + red[7];
    const float inv = 1.0f / sum;
    unsigned short* Pr = (unsigned short*)S + (bl * 2048 + i) * 4096;
#pragma unroll
    for (int c2 = 0; c2 < 8; ++c2)
        Pr[tid + c2 * 256] = f2bf(l[c2] * inv);
}

// ---------- Vt transpose ----------
__global__ __launch_bounds__(256) void transpose_v_kernel(
    const unsigned short* __restrict__ z, unsigned short* __restrict__ Vt, long sVtb)
{
    __shared__ unsigned short t[32][33];
    const int tid = threadIdx.x;
    const int tx = tid & 31, ty = tid >> 5;
    const long b = blockIdx.z;
    const long k0 = (long)blockIdx.x * 32, n0 = (long)blockIdx.y * 32;
#pragma unroll
    for (int r = 0; r < 32; r += 8)
        t[r + ty][tx] = z[(b * 2048 + k0 + r + ty) * 1088 + n0 + tx];
    __syncthreads();
#pragma unroll
    for (int r = 0; r < 32; r += 8)
        Vt[b * sVtb + (n0 + r + ty) * 2048 + k0 + tx] = t[tx][r + ty];
}

// ---------- weight cast-transpose ----------
__global__ __launch_bounds__(256) void cast_transpose_kernel(
    const float* __restrict__ W, unsigned short* __restrict__ Wt, int rows, int cols)
{
    __shared__ float t[32][33];
    const int tid = threadIdx.x;
    const int tx = tid & 31, ty = tid >> 5;
    const long r0 = (long)blockIdx.y * 32, c0 = (long)blockIdx.x * 32;
#pragma unroll
    for (int r = 0; r < 32; r += 8)
        t[r + ty][tx] = W[(r0 + r + ty) * (long)cols + c0 + tx];
    __syncthreads();
#pragma unroll
    for (int r = 0; r < 32; r += 8)
        Wt[(c0 + r + ty) * (long)rows + r0 + tx] = f2bf(t[tx][r + ty]);
}

// ---------- host ----------
extern "C" void kernel_launch(void* const* d_in, const int* in_sizes, int n_in,
                              void* d_out, int out_size, void* d_ws, size_t ws_size,
                              hipStream_t stream)
{
    const float* x   = (const float*)d_in[0];
    const float* L   = (const float*)d_in[1];
    const float* W1  = (const float*)d_in[2];
    const float* b1  = (const float*)d_in[3];
    const float* W2  = (const float*)d_in[4];
    const float* b2  = (const float*)d_in[5];
    const float* g1  = (const float*)d_in[6];
    const float* be1 = (const float*)d_in[7];
    const float* g2  = (const float*)d_in[8];
    const float* be2 = (const float*)d_in[9];
    float* out = (float*)d_out;
    unsigned short* z = (unsigned short*)d_out;

    char* wsp = (char*)d_ws;
    float* q = (float*)wsp;
    char* pool = wsp + 32768;
    unsigned short* Vt   = (unsigned short*)pool;
    float*          Smat = (float*)(pool + 16777216);
    unsigned short* W1t = (unsigned short*)pool;
    unsigned short* W2t = (unsigned short*)(pool + 8388608);
    unsigned short* hm  = (unsigned short*)(pool + 16777216);
    unsigned short* hid = (unsigned short*)(pool + 33554432);
    const bool fullMLP = ws_size >= (size_t)32768 + 100663296 + 65536;

    ln_kernel<<<8192, 256, 0, stream>>>(x, g1, be1, z, 1088, q, 1);
    u_kernel<<<8192, 256, 0, stream>>>(z, L, q);

    transpose_v_kernel<<<dim3(64, 32, 4), 256, 0, stream>>>(z, Vt, (long)1024 * 2048);

    // DIAGNOSTIC (ABL=6, 4 reps): stage + zero-sync probe. Garbage -> Smat,
    // overwritten by the real S-GEMM below. Dropped next round.
    gemm4r<256, 0, 6><<<dim3(8, 8, 4), 512, 0, stream>>>(
        z, 1088, (long)2048 * 1088,
        z, 1088, (long)2048 * 1088,
        Smat, 2048, (long)2048 * 2048,
        nullptr, 0, 0, nullptr, 1088);

    gemm4r<256, 0, 0><<<dim3(8, 8, 4), 512, 0, stream>>>(
        z, 1088, (long)2048 * 1088,
        z, 1088, (long)2048 * 1088,
        Smat, 2048, (long)2048 * 2048,
        nullptr, 0, 0, nullptr, 1088);
    softmax_kernel<<<dim3(2048, 4), 256, 0, stream>>>(Smat, q);
    gemm4r<128, 1, 0><<<dim3(8, 8, 4), 512, 0, stream>>>(
        (const unsigned short*)Smat, 4096, (long)2048 * 4096,
        Vt, 2048, (long)1024 * 2048,
        out, 1024, (long)2048 * 1024,
        x, 1024, (long)2048 * 1024,
        nullptr, 2048);

    cast_transpose_kernel<<<dim3(128, 32), 256, 0, stream>>>(W1, W1t, 1024, 4096);
    cast_transpose_kernel<<<dim3(32, 128), 256, 0, stream>>>(W2, W2t, 4096, 1024);
    ln_kernel<<<8192, 256, 0, stream>>>(out, g2, be2, hm, 1024, nullptr, 0);
    if (fullMLP) {
        gemm4r<256, 2, 0><<<dim3(16, 32, 1), 512, 0, stream>>>(
            hm, 1024, 0, W1t, 1024, 0,
            hid, 4096, 0, nullptr, 0, 0, b1, 1024);
        gemm4r<128, 3, 0><<<dim3(8, 32, 1), 512, 0, stream>>>(
            hid, 4096, 0, W2t, 4096, 0,
            out, 1024, 0, out, 1024, 0, b2, 4096);
    } else {
        for (int c = 0; c < 2; ++c) {
            const unsigned short* hmc = hm + (size_t)c * 4096 * 1024;
            float* oc = out + (size_t)c * 4096 * 1024;
            gemm4r<256, 2, 0><<<dim3(16, 16, 1), 512, 0, stream>>>(
                hmc, 1024, 0, W1t, 1024, 0,
                hid, 4096, 0, nullptr, 0, 0, b1, 1024);
            gemm4r<128, 3, 0><<<dim3(8, 16, 1), 512, 0, stream>>>(
                hid, 4096, 0, W2t, 4096, 0,
                oc, 1024, 0, oc, 1024, 0, b2, 4096);
        }
    }
}

// Round 10
// 392.561 us; speedup vs baseline: 1.3913x; 1.2172x over previous
//
#include <hip/hip_runtime.h>
#include <cstdint>

// ---------- types ----------
typedef float f32x4 __attribute__((ext_vector_type(4)));
typedef __bf16 bf16x8 __attribute__((ext_vector_type(8)));

#define AS1 __attribute__((address_space(1)))
#define AS3 __attribute__((address_space(3)))

__device__ __forceinline__ void gld_lds16(const void* g, void* l) {
    __builtin_amdgcn_global_load_lds((const AS1 void*)g, (AS3 void*)l, 16, 0, 0);
}

__device__ __forceinline__ unsigned short f2bf(float f) {  // RNE f32->bf16
    unsigned u = __builtin_bit_cast(unsigned, f);
    u = u + 0x7fffu + ((u >> 16) & 1u);
    return (unsigned short)(u >> 16);
}
__device__ __forceinline__ float bf2f(unsigned short h) {
    unsigned u = ((unsigned)h) << 16;
    return __builtin_bit_cast(float, u);
}

__device__ __forceinline__ void bar() {
    asm volatile("" ::: "memory");
    __builtin_amdgcn_s_barrier();
    asm volatile("" ::: "memory");
}

#define WAITVM(n) asm volatile("s_waitcnt vmcnt(" #n ")" ::: "memory")
#define LGKM0     asm volatile("s_waitcnt lgkmcnt(0)" ::: "memory")
#define SCHED0    __builtin_amdgcn_sched_barrier(0)

// ---------- 128x128 3-ring minimal-sync GEMM: C = A @ B^T, bf16, f32 accum --
// BK=32 (64B LDS rows), 4 waves (2x2), per-wave 64x64 output.
// LDS: THREE 16 KB buffers (A 128x64B + B 128x64B) = 48 KB -> 3 blocks/CU,
// 12 waves/CU: when one block sits at its tile barrier, two other blocks'
// MFMA streams cover the stall (m114 block-level TLP — unavailable at the
// R9 config's 1 block/CU, which R8/R9 probes showed was the 2x gap).
// Per K-tile: 8 ds_read_b128 + stage(t+2) (4 gld) + lgkmcnt(0) + 16 MFMA
// + ONE counted vmcnt(4) + ONE barrier.
// WAR: stage(t+2) targets buf (t+2)%3 = (t-1)%3; its readers (tile t-1)
//   drained via lgkmcnt(0) before the bar ending t-1; stages issue after.
// RAW: end-of-t vmcnt(4) leaves only stage(t+2) outstanding -> t+1 landed.
// Swizzle (R9-verified, 0 conflicts): source chunk ^= ((row>>1)&3); LDS
//   linear; frag k-chunk cc = (lane>>4)^((lane>>1)&3).
// MODE 0: C f32 = acc; 1: +add; 2: bf16 gelu(acc+bias); 3: f32 acc+bias+add
template<int MODE>
__global__ __launch_bounds__(256, 3) void gemm128(
    const unsigned short* __restrict__ A, long lda, long sAb,
    const unsigned short* __restrict__ B, long ldb, long sBb,
    void* C, long ldc, long sCb,
    const float* add, long ldadd, long sAddb,
    const float* __restrict__ bias, int K)
{
    constexpr int ABUF = 128 * 64;         // 8 KB
    constexpr int BUF  = 2 * ABUF;         // 16 KB (A + B)
    __shared__ char sm[3 * BUF];           // 48 KB
    const int tid = threadIdx.x, lane = tid & 63, wid = tid >> 6;
    const int wr = wid >> 1, wc = wid & 1;  // 2x2 wave grid, 64x64 each

    const long zb = blockIdx.z;
    // m204 bijective XCD swizzle
    const int nwg  = gridDim.x * gridDim.y;
    const int orig = blockIdx.y * gridDim.x + blockIdx.x;
    const int q8 = nwg >> 3, r8 = nwg & 7;
    const int xcd = orig & 7;
    const int wg  = (xcd < r8 ? xcd * (q8 + 1) : r8 * (q8 + 1) + (xcd - r8) * q8) + (orig >> 3);
    const int bx = wg % gridDim.x, by = wg / gridDim.x;

    const char* Ab = (const char*)(A + zb * sAb + (long)by * 128 * lda);
    const char* Bb = (const char*)(B + zb * sBb + (long)bx * 128 * ldb);
    const long ldaB = lda * 2, ldbB = ldb * 2;

    // stage one K-tile (A 128x64B + B 128x64B) into ring buffer b.
    // LDS dest linear (wave base + lane*16); global source chunk pre-swizzled.
    const long gsw = (long)(((tid & 3) ^ ((tid >> 3) & 3)) << 4);
    auto stage = [&](int kt, int b) {
#pragma unroll
        for (int i = 0; i < 2; ++i) {
            const int r = i * 64 + (tid >> 2);
            gld_lds16(Ab + (long)r * ldaB + (long)kt * 64 + gsw,
                      sm + b * BUF + i * 4096 + wid * 1024);
            gld_lds16(Bb + (long)r * ldbB + (long)kt * 64 + gsw,
                      sm + b * BUF + ABUF + i * 4096 + wid * 1024);
        }
    };

    f32x4 acc[4][4] = {};
    const int NT = K / 32;
    const int cc = ((lane >> 4) ^ ((lane >> 1) & 3)) << 4;   // frag k-chunk

    // prologue: tiles 0,1
    stage(0, 0); stage(1, 1);
    WAITVM(4);                              // tile0 landed (tile1's 4 pending)
    bar();

#pragma unroll 1
    for (int t = 0; t < NT; ++t) {
        const char* bufp = sm + (t % 3) * BUF;
        bf16x8 af[4], bfr[4];
#pragma unroll
        for (int m = 0; m < 4; ++m) {
            const int R = wr * 64 + m * 16 + (lane & 15);
            af[m] = *(const bf16x8*)(bufp + R * 64 + cc);
        }
#pragma unroll
        for (int n = 0; n < 4; ++n) {
            const int R = wc * 64 + n * 16 + (lane & 15);
            bfr[n] = *(const bf16x8*)(bufp + ABUF + R * 64 + cc);
        }
        if (t + 2 < NT) stage(t + 2, (t + 2) % 3);   // DMA overlaps MFMA
        LGKM0; SCHED0;
        __builtin_amdgcn_s_setprio(1);
#pragma unroll
        for (int m = 0; m < 4; ++m)
#pragma unroll
            for (int n = 0; n < 4; ++n)
                acc[m][n] = __builtin_amdgcn_mfma_f32_16x16x32_bf16(
                    af[m], bfr[n], acc[m][n], 0, 0, 0);
        __builtin_amdgcn_s_setprio(0);
        if (t + 1 < NT) {                   // single tile-end sync point
            if (t + 2 < NT) WAITVM(4); else WAITVM(0);
            bar();
        }
    }

    // epilogue: C/D layout col=lane&15, row=(lane>>4)*4+j
    const long row0 = (long)by * 128 + wr * 64 + (lane >> 4) * 4;
    const long col0 = (long)bx * 128 + wc * 64 + (lane & 15);
#pragma unroll
    for (int m = 0; m < 4; ++m)
#pragma unroll
        for (int n = 0; n < 4; ++n)
#pragma unroll
            for (int j = 0; j < 4; ++j) {
                const long r = row0 + m * 16 + j;
                const long c = col0 + n * 16;
                const float v = acc[m][n][j];
                if (MODE == 0) {
                    ((float*)C)[zb * sCb + r * ldc + c] = v;
                } else if (MODE == 1) {
                    ((float*)C)[zb * sCb + r * ldc + c] = v + add[zb * sAddb + r * ldadd + c];
                } else if (MODE == 2) {
                    float tt = v + bias[c];
                    float gl = 0.5f * tt * (1.0f + erff(tt * 0.70710678118654752f));
                    ((unsigned short*)C)[zb * sCb + r * ldc + c] = f2bf(gl);
                } else {
                    ((float*)C)[zb * sCb + r * ldc + c] = v + bias[c] + add[zb * sAddb + r * ldadd + c];
                }
            }
}

// ---------- LayerNorm ----------
__global__ __launch_bounds__(256) void ln_kernel(
    const float* __restrict__ x, const float* __restrict__ gamma, const float* __restrict__ beta,
    unsigned short* __restrict__ out, int ldout, float* qout, int pad)
{
    const int tid = threadIdx.x;
    const long row = blockIdx.x;
    float4 v = ((const float4*)(x + row * 1024))[tid];
    float s = v.x + v.y + v.z + v.w;
    float s2 = v.x * v.x + v.y * v.y + v.z * v.z + v.w * v.w;
#pragma unroll
    for (int off = 32; off; off >>= 1) {
        s  += __shfl_down(s, off);
        s2 += __shfl_down(s2, off);
    }
    __shared__ float red[12];
    const int lane = tid & 63, wid = tid >> 6;
    if (lane == 0) { red[wid] = s; red[4 + wid] = s2; }
    __syncthreads();
    s  = red[0] + red[1] + red[2] + red[3];
    s2 = red[4] + red[5] + red[6] + red[7];
    const float mu = s * (1.0f / 1024.0f);
    const float var = s2 * (1.0f / 1024.0f) - mu * mu;
    const float rs = rsqrtf(var + 1e-5f);
    const float4 g = ((const float4*)gamma)[tid];
    const float4 b = ((const float4*)beta)[tid];
    unsigned short o0 = f2bf((v.x - mu) * rs * g.x + b.x);
    unsigned short o1 = f2bf((v.y - mu) * rs * g.y + b.y);
    unsigned short o2 = f2bf((v.z - mu) * rs * g.z + b.z);
    unsigned short o3 = f2bf((v.w - mu) * rs * g.w + b.w);
    ushort4 ov; ov.x = o0; ov.y = o1; ov.z = o2; ov.w = o3;
    ((ushort4*)(out + row * (long)ldout))[tid] = ov;
    if (pad && tid < 32) out[row * (long)ldout + 1056 + tid] = 0;
    if (qout) {
        float y0 = bf2f(o0), y1 = bf2f(o1), y2 = bf2f(o2), y3 = bf2f(o3);
        float sq = y0 * y0 + y1 * y1 + y2 * y2 + y3 * y3;
#pragma unroll
        for (int off = 32; off; off >>= 1) sq += __shfl_down(sq, off);
        if (lane == 0) red[8 + wid] = sq;
        __syncthreads();
        if (tid == 0) qout[row] = red[8] + red[9] + red[10] + red[11];
    }
}

// ---------- u = hn @ L ----------
__global__ __launch_bounds__(256) void u_kernel(
    unsigned short* __restrict__ z, const float* __restrict__ L, float* __restrict__ q)
{
    const int tid = threadIdx.x;
    const long row = blockIdx.x;
    __shared__ float hn[1024];
    __shared__ float part[8][32];
    ushort4 uv = ((const ushort4*)(z + row * 1088))[tid];
    hn[tid * 4 + 0] = bf2f(uv.x);
    hn[tid * 4 + 1] = bf2f(uv.y);
    hn[tid * 4 + 2] = bf2f(uv.z);
    hn[tid * 4 + 3] = bf2f(uv.w);
    __syncthreads();
    const int j = tid & 31, grp = tid >> 5;
    float acc = 0.f;
    const float* Lp = L + j;
#pragma unroll 4
    for (int d = grp * 128; d < grp * 128 + 128; ++d)
        acc += hn[d] * Lp[(long)d * 32];
    part[grp][j] = acc;
    __syncthreads();
    if (tid < 32) {
        float u = 0.f;
#pragma unroll
        for (int g2 = 0; g2 < 8; ++g2) u += part[g2][tid];
        unsigned short ub = f2bf(u);
        z[row * 1088 + 1024 + tid] = ub;
        float uf = bf2f(ub);
        part[0][tid] = uf * uf;
    }
    __syncthreads();
    if (tid == 0) {
        float sq = 0.f;
#pragma unroll
        for (int t2 = 0; t2 < 32; ++t2) sq += part[0][t2];
        q[row] += sq;
    }
}

// ---------- softmax ----------
__global__ __launch_bounds__(256) void softmax_kernel(
    float* S, const float* qb)
{
    const int tid = threadIdx.x;
    const long i = blockIdx.x, bl = blockIdx.y;
    float* Sr = S + (bl * 2048 + i) * 2048;
    const float* qr = qb + bl * 2048;
    float l[8];
    float mx = -1e30f;
#pragma unroll
    for (int c2 = 0; c2 < 8; ++c2) {
        const int jj = tid + c2 * 256;
        l[c2] = 2.0f * Sr[jj] - qr[jj];
        mx = fmaxf(mx, l[c2]);
    }
#pragma unroll
    for (int off = 32; off; off >>= 1) mx = fmaxf(mx, __shfl_xor(mx, off));
    __shared__ float red[8];
    const int lane = tid & 63, wid = tid >> 6;
    if (lane == 0) red[wid] = mx;
    __syncthreads();
    mx = fmaxf(fmaxf(red[0], red[1]), fmaxf(red[2], red[3]));
    float sum = 0.f;
#pragma unroll
    for (int c2 = 0; c2 < 8; ++c2) { l[c2] = __expf(l[c2] - mx); sum += l[c2]; }
#pragma unroll
    for (int off = 32; off; off >>= 1) sum += __shfl_xor(sum, off);
    if (lane == 0) red[4 + wid] = sum;
    __syncthreads();
    sum = red[4] + red[5] + red[6] + red[7];
    const float inv = 1.0f / sum;
    unsigned short* Pr = (unsigned short*)S + (bl * 2048 + i) * 4096;
#pragma unroll
    for (int c2 = 0; c2 < 8; ++c2)
        Pr[tid + c2 * 256] = f2bf(l[c2] * inv);
}

// ---------- Vt transpose ----------
__global__ __launch_bounds__(256) void transpose_v_kernel(
    const unsigned short* __restrict__ z, unsigned short* __restrict__ Vt, long sVtb)
{
    __shared__ unsigned short t[32][33];
    const int tid = threadIdx.x;
    const int tx = tid & 31, ty = tid >> 5;
    const long b = blockIdx.z;
    const long k0 = (long)blockIdx.x * 32, n0 = (long)blockIdx.y * 32;
#pragma unroll
    for (int r = 0; r < 32; r += 8)
        t[r + ty][tx] = z[(b * 2048 + k0 + r + ty) * 1088 + n0 + tx];
    __syncthreads();
#pragma unroll
    for (int r = 0; r < 32; r += 8)
        Vt[b * sVtb + (n0 + r + ty) * 2048 + k0 + tx] = t[tx][r + ty];
}

// ---------- weight cast-transpose ----------
__global__ __launch_bounds__(256) void cast_transpose_kernel(
    const float* __restrict__ W, unsigned short* __restrict__ Wt, int rows, int cols)
{
    __shared__ float t[32][33];
    const int tid = threadIdx.x;
    const int tx = tid & 31, ty = tid >> 5;
    const long r0 = (long)blockIdx.y * 32, c0 = (long)blockIdx.x * 32;
#pragma unroll
    for (int r = 0; r < 32; r += 8)
        t[r + ty][tx] = W[(r0 + r + ty) * (long)cols + c0 + tx];
    __syncthreads();
#pragma unroll
    for (int r = 0; r < 32; r += 8)
        Wt[(c0 + r + ty) * (long)rows + r0 + tx] = f2bf(t[tx][r + ty]);
}

// ---------- host ----------
extern "C" void kernel_launch(void* const* d_in, const int* in_sizes, int n_in,
                              void* d_out, int out_size, void* d_ws, size_t ws_size,
                              hipStream_t stream)
{
    const float* x   = (const float*)d_in[0];
    const float* L   = (const float*)d_in[1];
    const float* W1  = (const float*)d_in[2];
    const float* b1  = (const float*)d_in[3];
    const float* W2  = (const float*)d_in[4];
    const float* b2  = (const float*)d_in[5];
    const float* g1  = (const float*)d_in[6];
    const float* be1 = (const float*)d_in[7];
    const float* g2  = (const float*)d_in[8];
    const float* be2 = (const float*)d_in[9];
    float* out = (float*)d_out;
    unsigned short* z = (unsigned short*)d_out;

    char* wsp = (char*)d_ws;
    float* q = (float*)wsp;
    char* pool = wsp + 32768;
    unsigned short* Vt   = (unsigned short*)pool;
    float*          Smat = (float*)(pool + 16777216);
    unsigned short* W1t = (unsigned short*)pool;
    unsigned short* W2t = (unsigned short*)(pool + 8388608);
    unsigned short* hm  = (unsigned short*)(pool + 16777216);
    unsigned short* hid = (unsigned short*)(pool + 33554432);
    const bool fullMLP = ws_size >= (size_t)32768 + 100663296 + 65536;

    ln_kernel<<<8192, 256, 0, stream>>>(x, g1, be1, z, 1088, q, 1);
    u_kernel<<<8192, 256, 0, stream>>>(z, L, q);

    transpose_v_kernel<<<dim3(64, 32, 4), 256, 0, stream>>>(z, Vt, (long)1024 * 2048);
    gemm128<0><<<dim3(16, 16, 4), 256, 0, stream>>>(
        z, 1088, (long)2048 * 1088,
        z, 1088, (long)2048 * 1088,
        Smat, 2048, (long)2048 * 2048,
        nullptr, 0, 0, nullptr, 1088);
    softmax_kernel<<<dim3(2048, 4), 256, 0, stream>>>(Smat, q);
    gemm128<1><<<dim3(8, 16, 4), 256, 0, stream>>>(
        (const unsigned short*)Smat, 4096, (long)2048 * 4096,
        Vt, 2048, (long)1024 * 2048,
        out, 1024, (long)2048 * 1024,
        x, 1024, (long)2048 * 1024,
        nullptr, 2048);

    cast_transpose_kernel<<<dim3(128, 32), 256, 0, stream>>>(W1, W1t, 1024, 4096);
    cast_transpose_kernel<<<dim3(32, 128), 256, 0, stream>>>(W2, W2t, 4096, 1024);
    ln_kernel<<<8192, 256, 0, stream>>>(out, g2, be2, hm, 1024, nullptr, 0);
    if (fullMLP) {
        gemm128<2><<<dim3(32, 64, 1), 256, 0, stream>>>(
            hm, 1024, 0, W1t, 1024, 0,
            hid, 4096, 0, nullptr, 0, 0, b1, 1024);
        gemm128<3><<<dim3(8, 64, 1), 256, 0, stream>>>(
            hid, 4096, 0, W2t, 4096, 0,
            out, 1024, 0, out, 1024, 0, b2, 4096);
    } else {
        for (int c = 0; c < 2; ++c) {
            const unsigned short* hmc = hm + (size_t)c * 4096 * 1024;
            float* oc = out + (size_t)c * 4096 * 1024;
            gemm128<2><<<dim3(32, 32, 1), 256, 0, stream>>>(
                hmc, 1024, 0, W1t, 1024, 0,
                hid, 4096, 0, nullptr, 0, 0, b1, 1024);
            gemm128<3><<<dim3(8, 32, 1), 256, 0, stream>>>(
                hid, 4096, 0, W2t, 4096, 0,
                oc, 1024, 0, oc, 1024, 0, b2, 4096);
        }
    }
}

// Round 11
// 383.207 us; speedup vs baseline: 1.4253x; 1.0244x over previous
//
#include <hip/hip_runtime.h>
#include <cstdint>

// ---------- types ----------
typedef float f32x4 __attribute__((ext_vector_type(4)));
typedef __bf16 bf16x8 __attribute__((ext_vector_type(8)));

#define AS1 __attribute__((address_space(1)))
#define AS3 __attribute__((address_space(3)))

__device__ __forceinline__ void gld_lds16(const void* g, void* l) {
    __builtin_amdgcn_global_load_lds((const AS1 void*)g, (AS3 void*)l, 16, 0, 0);
}

__device__ __forceinline__ unsigned short f2bf(float f) {  // RNE f32->bf16
    unsigned u = __builtin_bit_cast(unsigned, f);
    u = u + 0x7fffu + ((u >> 16) & 1u);
    return (unsigned short)(u >> 16);
}
__device__ __forceinline__ float bf2f(unsigned short h) {
    unsigned u = ((unsigned)h) << 16;
    return __builtin_bit_cast(float, u);
}

__device__ __forceinline__ void bar() {
    asm volatile("" ::: "memory");
    __builtin_amdgcn_s_barrier();
    asm volatile("" ::: "memory");
}

#define WAITVM(n) asm volatile("s_waitcnt vmcnt(" #n ")" ::: "memory")
#define LGKM0     asm volatile("s_waitcnt lgkmcnt(0)" ::: "memory")
#define SCHED0    __builtin_amdgcn_sched_barrier(0)

// ---------- 128x128 3-ring minimal-sync GEMM: C = A @ B^T, bf16, f32 accum --
// BK=32, 4 waves (2x2), 3 x 16KB LDS ring -> 3 blocks/CU (R10-verified core).
// TRI=0: rectangular grid + m204 XCD swizzle (R10 behavior).
// TRI=1: SYMMETRIC C (A==B): grid.x = 136 = lower-triangle tiles of 16x16.
//   Decode in 2-row bands, col-major within band (band k = rows {2k,2k+1},
//   cum(k)=2k^2+k): XCD chunk of 17 tiles touches ~2 A + ~9 B panels
//   (~2.9 MB <= 4 MB L2; fixes R10's 12x over-fetch, FETCH 211 MB).
//   Off-diagonal blocks ALSO store the transposed tile (mirror): per (m,n)
//   acc[m][n] is 4 row-consecutive f32 -> one float4 at [c][row0+m*16];
//   lane groups {l,l+16,l+32,l+48} form 64B contiguous segments.
// MODE 0: C f32 = acc; 1: +add; 2: bf16 gelu(acc+bias); 3: f32 acc+bias+add
template<int MODE, int TRI>
__global__ __launch_bounds__(256, 3) void gemm128(
    const unsigned short* __restrict__ A, long lda, long sAb,
    const unsigned short* __restrict__ B, long ldb, long sBb,
    void* C, long ldc, long sCb,
    const float* add, long ldadd, long sAddb,
    const float* __restrict__ bias, int K)
{
    constexpr int ABUF = 128 * 64;         // 8 KB
    constexpr int BUF  = 2 * ABUF;         // 16 KB (A + B)
    __shared__ char sm[3 * BUF];           // 48 KB
    const int tid = threadIdx.x, lane = tid & 63, wid = tid >> 6;
    const int wr = wid >> 1, wc = wid & 1;  // 2x2 wave grid, 64x64 each

    const long zb = blockIdx.z;
    // m204 bijective XCD swizzle
    const int nwg  = gridDim.x * gridDim.y;
    const int orig = blockIdx.y * gridDim.x + blockIdx.x;
    const int q8 = nwg >> 3, r8 = nwg & 7;
    const int xcd = orig & 7;
    const int wg  = (xcd < r8 ? xcd * (q8 + 1) : r8 * (q8 + 1) + (xcd - r8) * q8) + (orig >> 3);
    int bx, by;
    if constexpr (TRI == 1) {
        // triangle decode: band k (rows 2k,2k+1), col-major within band
        int k = 0;
        while (2 * (k + 1) * (k + 1) + (k + 1) <= wg) ++k;
        const int i = wg - (2 * k * k + k);
        const int R = 2 * k;
        if (i < 2 * (R + 1)) { by = R + (i & 1); bx = i >> 1; }
        else                 { by = R + 1;      bx = R + 1;  }
    } else {
        bx = wg % gridDim.x; by = wg / gridDim.x;
    }

    const char* Ab = (const char*)(A + zb * sAb + (long)by * 128 * lda);
    const char* Bb = (const char*)(B + zb * sBb + (long)bx * 128 * ldb);
    const long ldaB = lda * 2, ldbB = ldb * 2;

    // stage one K-tile (A 128x64B + B 128x64B) into ring buffer b.
    const long gsw = (long)(((tid & 3) ^ ((tid >> 3) & 3)) << 4);
    auto stage = [&](int kt, int b) {
#pragma unroll
        for (int i = 0; i < 2; ++i) {
            const int r = i * 64 + (tid >> 2);
            gld_lds16(Ab + (long)r * ldaB + (long)kt * 64 + gsw,
                      sm + b * BUF + i * 4096 + wid * 1024);
            gld_lds16(Bb + (long)r * ldbB + (long)kt * 64 + gsw,
                      sm + b * BUF + ABUF + i * 4096 + wid * 1024);
        }
    };

    f32x4 acc[4][4] = {};
    const int NT = K / 32;
    const int cc = ((lane >> 4) ^ ((lane >> 1) & 3)) << 4;   // frag k-chunk

    stage(0, 0); stage(1, 1);
    WAITVM(4);
    bar();

#pragma unroll 1
    for (int t = 0; t < NT; ++t) {
        const char* bufp = sm + (t % 3) * BUF;
        bf16x8 af[4], bfr[4];
#pragma unroll
        for (int m = 0; m < 4; ++m) {
            const int R = wr * 64 + m * 16 + (lane & 15);
            af[m] = *(const bf16x8*)(bufp + R * 64 + cc);
        }
#pragma unroll
        for (int n = 0; n < 4; ++n) {
            const int R = wc * 64 + n * 16 + (lane & 15);
            bfr[n] = *(const bf16x8*)(bufp + ABUF + R * 64 + cc);
        }
        if (t + 2 < NT) stage(t + 2, (t + 2) % 3);
        LGKM0; SCHED0;
        __builtin_amdgcn_s_setprio(1);
#pragma unroll
        for (int m = 0; m < 4; ++m)
#pragma unroll
            for (int n = 0; n < 4; ++n)
                acc[m][n] = __builtin_amdgcn_mfma_f32_16x16x32_bf16(
                    af[m], bfr[n], acc[m][n], 0, 0, 0);
        __builtin_amdgcn_s_setprio(0);
        if (t + 1 < NT) {
            if (t + 2 < NT) WAITVM(4); else WAITVM(0);
            bar();
        }
    }

    // epilogue: C/D layout col=lane&15, row=(lane>>4)*4+j
    const long row0 = (long)by * 128 + wr * 64 + (lane >> 4) * 4;
    const long col0 = (long)bx * 128 + wc * 64 + (lane & 15);
#pragma unroll
    for (int m = 0; m < 4; ++m)
#pragma unroll
        for (int n = 0; n < 4; ++n)
#pragma unroll
            for (int j = 0; j < 4; ++j) {
                const long r = row0 + m * 16 + j;
                const long c = col0 + n * 16;
                const float v = acc[m][n][j];
                if (MODE == 0) {
                    ((float*)C)[zb * sCb + r * ldc + c] = v;
                } else if (MODE == 1) {
                    ((float*)C)[zb * sCb + r * ldc + c] = v + add[zb * sAddb + r * ldadd + c];
                } else if (MODE == 2) {
                    float tt = v + bias[c];
                    float gl = 0.5f * tt * (1.0f + erff(tt * 0.70710678118654752f));
                    ((unsigned short*)C)[zb * sCb + r * ldc + c] = f2bf(gl);
                } else {
                    ((float*)C)[zb * sCb + r * ldc + c] = v + bias[c] + add[zb * sAddb + r * ldadd + c];
                }
            }
    if constexpr (TRI == 1) {
        if (by != bx) {   // mirror: C[c][r] = C[r][c] (f32x4 over j is r-contiguous)
#pragma unroll
            for (int m = 0; m < 4; ++m)
#pragma unroll
                for (int n = 0; n < 4; ++n) {
                    float* dst = (float*)C + zb * sCb + (col0 + n * 16) * ldc + (row0 + m * 16);
                    *(float4*)dst = (float4){acc[m][n][0], acc[m][n][1], acc[m][n][2], acc[m][n][3]};
                }
        }
    }
}

// ---------- LayerNorm ----------
__global__ __launch_bounds__(256) void ln_kernel(
    const float* __restrict__ x, const float* __restrict__ gamma, const float* __restrict__ beta,
    unsigned short* __restrict__ out, int ldout, float* qout, int pad)
{
    const int tid = threadIdx.x;
    const long row = blockIdx.x;
    float4 v = ((const float4*)(x + row * 1024))[tid];
    float s = v.x + v.y + v.z + v.w;
    float s2 = v.x * v.x + v.y * v.y + v.z * v.z + v.w * v.w;
#pragma unroll
    for (int off = 32; off; off >>= 1) {
        s  += __shfl_down(s, off);
        s2 += __shfl_down(s2, off);
    }
    __shared__ float red[12];
    const int lane = tid & 63, wid = tid >> 6;
    if (lane == 0) { red[wid] = s; red[4 + wid] = s2; }
    __syncthreads();
    s  = red[0] + red[1] + red[2] + red[3];
    s2 = red[4] + red[5] + red[6] + red[7];
    const float mu = s * (1.0f / 1024.0f);
    const float var = s2 * (1.0f / 1024.0f) - mu * mu;
    const float rs = rsqrtf(var + 1e-5f);
    const float4 g = ((const float4*)gamma)[tid];
    const float4 b = ((const float4*)beta)[tid];
    unsigned short o0 = f2bf((v.x - mu) * rs * g.x + b.x);
    unsigned short o1 = f2bf((v.y - mu) * rs * g.y + b.y);
    unsigned short o2 = f2bf((v.z - mu) * rs * g.z + b.z);
    unsigned short o3 = f2bf((v.w - mu) * rs * g.w + b.w);
    ushort4 ov; ov.x = o0; ov.y = o1; ov.z = o2; ov.w = o3;
    ((ushort4*)(out + row * (long)ldout))[tid] = ov;
    if (pad && tid < 32) out[row * (long)ldout + 1056 + tid] = 0;
    if (qout) {
        float y0 = bf2f(o0), y1 = bf2f(o1), y2 = bf2f(o2), y3 = bf2f(o3);
        float sq = y0 * y0 + y1 * y1 + y2 * y2 + y3 * y3;
#pragma unroll
        for (int off = 32; off; off >>= 1) sq += __shfl_down(sq, off);
        if (lane == 0) red[8 + wid] = sq;
        __syncthreads();
        if (tid == 0) qout[row] = red[8] + red[9] + red[10] + red[11];
    }
}

// ---------- u = hn @ L ----------
__global__ __launch_bounds__(256) void u_kernel(
    unsigned short* __restrict__ z, const float* __restrict__ L, float* __restrict__ q)
{
    const int tid = threadIdx.x;
    const long row = blockIdx.x;
    __shared__ float hn[1024];
    __shared__ float part[8][32];
    ushort4 uv = ((const ushort4*)(z + row * 1088))[tid];
    hn[tid * 4 + 0] = bf2f(uv.x);
    hn[tid * 4 + 1] = bf2f(uv.y);
    hn[tid * 4 + 2] = bf2f(uv.z);
    hn[tid * 4 + 3] = bf2f(uv.w);
    __syncthreads();
    const int j = tid & 31, grp = tid >> 5;
    float acc = 0.f;
    const float* Lp = L + j;
#pragma unroll 4
    for (int d = grp * 128; d < grp * 128 + 128; ++d)
        acc += hn[d] * Lp[(long)d * 32];
    part[grp][j] = acc;
    __syncthreads();
    if (tid < 32) {
        float u = 0.f;
#pragma unroll
        for (int g2 = 0; g2 < 8; ++g2) u += part[g2][tid];
        unsigned short ub = f2bf(u);
        z[row * 1088 + 1024 + tid] = ub;
        float uf = bf2f(ub);
        part[0][tid] = uf * uf;
    }
    __syncthreads();
    if (tid == 0) {
        float sq = 0.f;
#pragma unroll
        for (int t2 = 0; t2 < 32; ++t2) sq += part[0][t2];
        q[row] += sq;
    }
}

// ---------- softmax ----------
__global__ __launch_bounds__(256) void softmax_kernel(
    float* S, const float* qb)
{
    const int tid = threadIdx.x;
    const long i = blockIdx.x, bl = blockIdx.y;
    float* Sr = S + (bl * 2048 + i) * 2048;
    const float* qr = qb + bl * 2048;
    float l[8];
    float mx = -1e30f;
#pragma unroll
    for (int c2 = 0; c2 < 8; ++c2) {
        const int jj = tid + c2 * 256;
        l[c2] = 2.0f * Sr[jj] - qr[jj];
        mx = fmaxf(mx, l[c2]);
    }
#pragma unroll
    for (int off = 32; off; off >>= 1) mx = fmaxf(mx, __shfl_xor(mx, off));
    __shared__ float red[8];
    const int lane = tid & 63, wid = tid >> 6;
    if (lane == 0) red[wid] = mx;
    __syncthreads();
    mx = fmaxf(fmaxf(red[0], red[1]), fmaxf(red[2], red[3]));
    float sum = 0.f;
#pragma unroll
    for (int c2 = 0; c2 < 8; ++c2) { l[c2] = __expf(l[c2] - mx); sum += l[c2]; }
#pragma unroll
    for (int off = 32; off; off >>= 1) sum += __shfl_xor(sum, off);
    if (lane == 0) red[4 + wid] = sum;
    __syncthreads();
    sum = red[4] + red[5] + red[6] + red[7];
    const float inv = 1.0f / sum;
    unsigned short* Pr = (unsigned short*)S + (bl * 2048 + i) * 4096;
#pragma unroll
    for (int c2 = 0; c2 < 8; ++c2)
        Pr[tid + c2 * 256] = f2bf(l[c2] * inv);
}

// ---------- Vt transpose ----------
__global__ __launch_bounds__(256) void transpose_v_kernel(
    const unsigned short* __restrict__ z, unsigned short* __restrict__ Vt, long sVtb)
{
    __shared__ unsigned short t[32][33];
    const int tid = threadIdx.x;
    const int tx = tid & 31, ty = tid >> 5;
    const long b = blockIdx.z;
    const long k0 = (long)blockIdx.x * 32, n0 = (long)blockIdx.y * 32;
#pragma unroll
    for (int r = 0; r < 32; r += 8)
        t[r + ty][tx] = z[(b * 2048 + k0 + r + ty) * 1088 + n0 + tx];
    __syncthreads();
#pragma unroll
    for (int r = 0; r < 32; r += 8)
        Vt[b * sVtb + (n0 + r + ty) * 2048 + k0 + tx] = t[tx][r + ty];
}

// ---------- weight cast-transpose ----------
__global__ __launch_bounds__(256) void cast_transpose_kernel(
    const float* __restrict__ W, unsigned short* __restrict__ Wt, int rows, int cols)
{
    __shared__ float t[32][33];
    const int tid = threadIdx.x;
    const int tx = tid & 31, ty = tid >> 5;
    const long r0 = (long)blockIdx.y * 32, c0 = (long)blockIdx.x * 32;
#pragma unroll
    for (int r = 0; r < 32; r += 8)
        t[r + ty][tx] = W[(r0 + r + ty) * (long)cols + c0 + tx];
    __syncthreads();
#pragma unroll
    for (int r = 0; r < 32; r += 8)
        Wt[(c0 + r + ty) * (long)rows + r0 + tx] = f2bf(t[tx][r + ty]);
}

// ---------- host ----------
extern "C" void kernel_launch(void* const* d_in, const int* in_sizes, int n_in,
                              void* d_out, int out_size, void* d_ws, size_t ws_size,
                              hipStream_t stream)
{
    const float* x   = (const float*)d_in[0];
    const float* L   = (const float*)d_in[1];
    const float* W1  = (const float*)d_in[2];
    const float* b1  = (const float*)d_in[3];
    const float* W2  = (const float*)d_in[4];
    const float* b2  = (const float*)d_in[5];
    const float* g1  = (const float*)d_in[6];
    const float* be1 = (const float*)d_in[7];
    const float* g2  = (const float*)d_in[8];
    const float* be2 = (const float*)d_in[9];
    float* out = (float*)d_out;
    unsigned short* z = (unsigned short*)d_out;

    char* wsp = (char*)d_ws;
    float* q = (float*)wsp;
    char* pool = wsp + 32768;
    unsigned short* Vt   = (unsigned short*)pool;
    float*          Smat = (float*)(pool + 16777216);
    unsigned short* W1t = (unsigned short*)pool;
    unsigned short* W2t = (unsigned short*)(pool + 8388608);
    unsigned short* hm  = (unsigned short*)(pool + 16777216);
    unsigned short* hid = (unsigned short*)(pool + 33554432);
    const bool fullMLP = ws_size >= (size_t)32768 + 100663296 + 65536;

    ln_kernel<<<8192, 256, 0, stream>>>(x, g1, be1, z, 1088, q, 1);
    u_kernel<<<8192, 256, 0, stream>>>(z, L, q);

    transpose_v_kernel<<<dim3(64, 32, 4), 256, 0, stream>>>(z, Vt, (long)1024 * 2048);
    // S = z z^T is symmetric: lower-triangle tiles only (136 of 256) + mirror
    gemm128<0, 1><<<dim3(136, 1, 4), 256, 0, stream>>>(
        z, 1088, (long)2048 * 1088,
        z, 1088, (long)2048 * 1088,
        Smat, 2048, (long)2048 * 2048,
        nullptr, 0, 0, nullptr, 1088);
    softmax_kernel<<<dim3(2048, 4), 256, 0, stream>>>(Smat, q);
    gemm128<1, 0><<<dim3(8, 16, 4), 256, 0, stream>>>(
        (const unsigned short*)Smat, 4096, (long)2048 * 4096,
        Vt, 2048, (long)1024 * 2048,
        out, 1024, (long)2048 * 1024,
        x, 1024, (long)2048 * 1024,
        nullptr, 2048);

    cast_transpose_kernel<<<dim3(128, 32), 256, 0, stream>>>(W1, W1t, 1024, 4096);
    cast_transpose_kernel<<<dim3(32, 128), 256, 0, stream>>>(W2, W2t, 4096, 1024);
    ln_kernel<<<8192, 256, 0, stream>>>(out, g2, be2, hm, 1024, nullptr, 0);
    if (fullMLP) {
        gemm128<2, 0><<<dim3(32, 64, 1), 256, 0, stream>>>(
            hm, 1024, 0, W1t, 1024, 0,
            hid, 4096, 0, nullptr, 0, 0, b1, 1024);
        gemm128<3, 0><<<dim3(8, 64, 1), 256, 0, stream>>>(
            hid, 4096, 0, W2t, 4096, 0,
            out, 1024, 0, out, 1024, 0, b2, 4096);
    } else {
        for (int c = 0; c < 2; ++c) {
            const unsigned short* hmc = hm + (size_t)c * 4096 * 1024;
            float* oc = out + (size_t)c * 4096 * 1024;
            gemm128<2, 0><<<dim3(32, 32, 1), 256, 0, stream>>>(
                hmc, 1024, 0, W1t, 1024, 0,
                hid, 4096, 0, nullptr, 0, 0, b1, 1024);
            gemm128<3, 0><<<dim3(8, 32, 1), 256, 0, stream>>>(
                hid, 4096, 0, W2t, 4096, 0,
                oc, 1024, 0, oc, 1024, 0, b2, 4096);
        }
    }
}